// Round 7
// baseline (119.719 us; speedup 1.0000x reference)
//
#include <hip/hip_runtime.h>

#define THRESH 0.95f
#define MAXL 64
#define BPB   16    // batches per scan block (lanes 0..15 of wave 0)
#define SSTR  2012  // LDS float stride per lane: 2012%32=28 -> 2-way b128 conflict (free)
#define RSLOT 66    // LDS record stride (uint2): (4L+2idx)%32 -> 2-way (free)
#define RSTR  65    // global records per batch: 64 labels + 1 dump slot

// Kernel A v7: branchless lane-parallel scan, LDS-only recording.
// Bit-exact chain per step: x = integ + a; f = x > 0.95; integ = f ? x-1 : x
// (x-1 is Sterbenz-exact; identical op order to the reference).
// Recording without branches: every step ds_write_b64 {pre, t} to LDS slot
// min(n,64); n increments only on fire, so each slot's final value is its
// fire record (slot 64 = dump, as the reference's MAXL+1 slot).
// No global stores in the loop (v6's killer: 32-line scatter per store).
// Alphas staged coalesced global->LDS, then ds_read_b128 per 4 steps with
// two-phase p/q named-buffer prefetch (8-16 step lookahead, zero movs).
__global__ __launch_bounds__(256) void cif_scan(
    const float* __restrict__ alphas, int T, int B,
    int* __restrict__ nf, uint2* __restrict__ recs) {
    __shared__ __align__(16) float sa[BPB * SSTR + 16];
    __shared__ uint2 rec_lds[BPB * RSLOT];
    int b0 = blockIdx.x * BPB;
    int tid = threadIdx.x;
    int nb = B - b0; if (nb > BPB) nb = BPB;

    // ---- stage: rows b0..b0+nb-1 (contiguous in global) -> sa[row*SSTR + t]
    const float* gbase = alphas + (size_t)b0 * T;
    if ((T & 3) == 0 && ((((uintptr_t)gbase) & 15) == 0)) {
        int R4 = T >> 2;
        const float4* g4 = (const float4*)gbase;
        int tot4 = nb * R4;
        for (int i = tid; i < tot4; i += 256) {
            int r = i / R4, c = i - r * R4;
            *(float4*)&sa[r * SSTR + (c << 2)] = g4[i];
        }
    } else {
        for (int i = tid; i < nb * T; i += 256) {
            int r = i / T, c = i - r * T;
            sa[r * SSTR + c] = gbase[(size_t)r * T + c];
        }
    }
    __syncthreads();

    if (tid < nb) {
        int L = tid;
        const float4* s4 = (const float4*)&sa[L * SSTR];
        uint2* rl = &rec_lds[L * RSLOT];
        float integ = 0.0f;
        unsigned n = 0;
        unsigned tcur = 0;

#define ONESTEP(AV)                                                          \
    {                                                                        \
        float pre = integ;                                                   \
        float x = pre + (AV);                                                \
        float y = x - 1.0f;                                                  \
        bool f = x > THRESH;                                                 \
        integ = f ? y : x;                                                   \
        unsigned idx = (n < 64u) ? n : 64u;                                  \
        rl[idx] = make_uint2(__float_as_uint(pre), tcur);                    \
        ++tcur;                                                              \
        n += f ? 1u : 0u;                                                    \
    }
#define STEP4(CF) { ONESTEP((CF).x) ONESTEP((CF).y) ONESTEP((CF).z) ONESTEP((CF).w) }

        int ng = T >> 2;    // float4 groups
        int Tm = 0;
        if (ng >= 8) {
            float4 p0 = s4[0], p1 = s4[1], q0, q1;
            int g = 0;
            for (; g + 8 <= ng; g += 4) {
                q0 = s4[g + 2]; q1 = s4[g + 3];   // prefetch steps +8..+15
                STEP4(p0) STEP4(p1)
                p0 = s4[g + 4]; p1 = s4[g + 5];   // prefetch steps +16..+23
                STEP4(q0) STEP4(q1)
            }
            // p0,p1 hold groups g, g+1 (valid: g+1 < ng since loop exited with g+8 > ng >= 8)
            STEP4(p0) STEP4(p1)
            Tm = (g + 2) << 2;
        }
        for (int t = Tm; t < T; ++t) {            // scalar tail (<= 24 steps)
            float a = sa[L * SSTR + t];
            ONESTEP(a)
        }
#undef STEP4
#undef ONESTEP
        nf[b0 + L] = (n < 64u) ? (int)n : 64;
    }
    __syncthreads();

    // ---- flush records LDS -> global (once)
    int tot = nb * RSTR;
    for (int i = tid; i < tot; i += 256) {
        int r = i / RSTR, c = i - r * RSTR;
        recs[(size_t)(b0 + r) * RSTR + c] = rec_lds[r * RSLOT + c];
    }
}

// Kernel B (at HBM roofline, unchanged math): one block per (batch, label),
// float4 over H, ascending-t accumulation (absmax 0.0 in rounds 1-6).
//   out[b,k,:] = rem[k-1]*h[tp] + sum_{t in (tp,tf)} a_t*h[t] + dc_k*h[tf]
// dc = 1 - pre (bit-exact reference dist_completion), rem = a[tp] - dc_prev.
// Labels k >= fire count write zeros (d_out is poisoned by the harness).
__global__ __launch_bounds__(128) void cif_gather(
    const float* __restrict__ hidden, const float* __restrict__ alphas,
    int T, int H,
    const int* __restrict__ nf, const uint2* __restrict__ recs,
    float* __restrict__ out) {
    int b = blockIdx.x >> 6;
    int k = blockIdx.x & (MAXL - 1);

    int valid = (k < nf[b]);
    int tf = 0, t0 = 0, tp = 0;
    float rw = 0.0f, cw = 0.0f;
    const float* arow = alphas + (size_t)b * T;
    if (valid) {
        uint2 r = recs[(size_t)b * RSTR + k];
        cw = 1.0f - __uint_as_float(r.x);            // dc = 1 - pre, bit-exact
        tf = (int)r.y;
        if (k > 0) {
            uint2 rp = recs[(size_t)b * RSTR + k - 1];
            tp = (int)rp.y;
            float dcp = 1.0f - __uint_as_float(rp.x);
            rw = arow[tp] - dcp;                     // rem = a - dc, bit-exact
            t0 = tp + 1;
        }
    }

    if ((H & 3) == 0) {
        int W = H >> 2;
        const float4* hb4 = (const float4*)(hidden + (size_t)b * T * H);
        float4* out4 = (float4*)(out + (size_t)blockIdx.x * H);
        for (int h4 = threadIdx.x; h4 < W; h4 += blockDim.x) {
            float4 acc = make_float4(0.f, 0.f, 0.f, 0.f);
            if (valid) {
                if (k > 0) {
                    float4 m = hb4[(size_t)tp * W + h4];
                    acc.x = rw * m.x; acc.y = rw * m.y;
                    acc.z = rw * m.z; acc.w = rw * m.w;
                }
                for (int t = t0; t < tf; ++t) {
                    float4 m = hb4[(size_t)t * W + h4];
                    float a = arow[t];
                    acc.x += a * m.x; acc.y += a * m.y;
                    acc.z += a * m.z; acc.w += a * m.w;
                }
                float4 m = hb4[(size_t)tf * W + h4];
                acc.x += cw * m.x; acc.y += cw * m.y;
                acc.z += cw * m.z; acc.w += cw * m.w;
            }
            out4[h4] = acc;
        }
    } else {
        const float* hb = hidden + (size_t)b * T * H;
        size_t obase = (size_t)blockIdx.x * H;
        for (int h = threadIdx.x; h < H; h += blockDim.x) {
            float acc = 0.0f;
            if (valid) {
                if (k > 0) acc = rw * hb[(size_t)tp * H + h];
                for (int t = t0; t < tf; ++t)
                    acc += arow[t] * hb[(size_t)t * H + h];
                acc += cw * hb[(size_t)tf * H + h];
            }
            out[obase + h] = acc;
        }
    }
}

extern "C" void kernel_launch(void* const* d_in, const int* in_sizes, int n_in,
                              void* d_out, int out_size, void* d_ws, size_t ws_size,
                              hipStream_t stream) {
    const float* hidden = (const float*)d_in[0];
    const float* alphas = (const float*)d_in[1];
    float* out = (float*)d_out;

    long BT  = in_sizes[1];          // B*T
    long BTH = in_sizes[0];          // B*T*H
    int H = (int)(BTH / BT);         // 512
    int B = (int)((long)out_size / ((long)MAXL * H)); // 32
    int T = (int)(BT / B);           // 2000 (T*4B per lane must fit SSTR: 2000 <= 2012)

    char* ws = (char*)d_ws;
    int*   nf   = (int*)ws;                          // B ints
    uint2* recs = (uint2*)(ws + 256);                // B*RSTR uint2

    int nblk = (B + BPB - 1) / BPB;
    cif_scan<<<nblk, 256, 0, stream>>>(alphas, T, B, nf, recs);
    cif_gather<<<B * MAXL, 128, 0, stream>>>(hidden, alphas, T, H, nf, recs, out);
}

// Round 8
// 65.451 us; speedup vs baseline: 1.8291x; 1.8291x over previous
//
#include <hip/hip_runtime.h>

#define THRESH 0.95f
#define MAXL 64
#define RSTR 65     // records per batch: 64 labels + 1 spare
#define WPB  16     // waves (= batches) per scan block
#define SAFL (WPB * 2048 + 16)   // LDS floats: supports T <= 2048 (+prefetch pad)

// Kernel A v8: multi-wave speculative-window scan.
// One block = 16 waves = 16 batches (wave leader lane does the serial chain;
// 4 waves/SIMD so dependent-add latency is hidden cross-wave).
// Window of 8: 8 chained adds s0..s7 are a bit-exact prefix of the reference
// chain while no fire occurs. Since alphas > 0 (runtime-verified via sign-bit
// OR during staging), partials are monotone -> single test s7 > 0.95.
// Fired/negative windows take an exact serial replay (records {pre,t}; the
// reference's dist_completion = 1-pre and remainds = a-(1-pre) are
// recomputed bit-exactly in the gather, as proven in rounds 6-7).
__global__ __launch_bounds__(1024) void cif_scan(
    const float* __restrict__ alphas, int T, int B,
    int* __restrict__ nf, uint2* __restrict__ recs) {
    __shared__ __align__(16) float sa[SAFL];
    __shared__ int negf;
    int tid = threadIdx.x;
    int b0 = blockIdx.x * WPB;
    int nb = B - b0; if (nb > WPB) nb = WPB;
    if (tid == 0) negf = 0;
    __syncthreads();

    // ---- stage nb contiguous rows -> sa[r*T + t], OR-accumulate sign bits
    const float* gbase = alphas + (size_t)b0 * T;
    unsigned sgn = 0;
    bool fastld = ((T & 3) == 0) && ((((uintptr_t)gbase) & 15) == 0);
    if (fastld) {
        int R4 = T >> 2;
        const float4* g4 = (const float4*)gbase;
        int tot4 = nb * R4;
        for (int i = tid; i < tot4; i += 1024) {
            float4 v = g4[i];
            int r = i / R4, c = i - r * R4;
            *(float4*)&sa[r * T + (c << 2)] = v;
            sgn |= __float_as_uint(v.x) | __float_as_uint(v.y)
                 | __float_as_uint(v.z) | __float_as_uint(v.w);
        }
    } else {
        for (int i = tid; i < nb * T; i += 1024) {
            int r = i / T, c = i - r * T;
            float v = gbase[(size_t)r * T + c];
            sa[r * T + c] = v;
            sgn |= __float_as_uint(v);
        }
    }
    if (sgn & 0x80000000u) atomicOr(&negf, 1);
    __syncthreads();

    int wv = tid >> 6;                 // wave id = batch slot
    if ((tid & 63) != 0 || wv >= nb) return;
    int b = b0 + wv;
    bool neg = negf != 0;

    uint2* rec = recs + (size_t)b * RSTR;
    const float* row = &sa[wv * T];
    float integ = 0.0f;
    unsigned n = 0;

#define FIXUP(Xa, Xb, WIDX)                                                  \
    {                                                                        \
        float cur = v0;                                                      \
        float vv[8] = {Xa.x, Xa.y, Xa.z, Xa.w, Xb.x, Xb.y, Xb.z, Xb.w};      \
        _Pragma("unroll")                                                    \
        for (int ii = 0; ii < 8; ++ii) {                                     \
            float p = cur;                                                   \
            float x = p + vv[ii];                                            \
            if (x > THRESH) {                                                \
                if (n < MAXL)                                                \
                    rec[n] = make_uint2(__float_as_uint(p),                  \
                                        (unsigned)((WIDX) * 8 + ii));        \
                ++n;                                                         \
                x = x - 1.0f;                                                \
            }                                                                \
            cur = x;                                                         \
        }                                                                    \
        integ = cur;                                                         \
    }

// consume window WIDX held in Xa/Xb; prefetch window LIDX into Ya/Yb
#define DOWIN(Xa, Xb, Ya, Yb, WIDX, LIDX)                                    \
    {                                                                        \
        float v0 = integ;                                                    \
        Ya = s4[(LIDX) * 2]; Yb = s4[(LIDX) * 2 + 1];                        \
        float s0 = v0 + Xa.x;  float s1 = s0 + Xa.y;                         \
        float s2 = s1 + Xa.z;  float s3 = s2 + Xa.w;                         \
        float u4 = s3 + Xb.x;  float u5 = u4 + Xb.y;                         \
        float u6 = u5 + Xb.z;  float u7 = u6 + Xb.w;                         \
        if (__builtin_expect((u7 > THRESH) || neg, 0)) {                     \
            FIXUP(Xa, Xb, WIDX)                                              \
        } else {                                                             \
            integ = u7;                                                      \
        }                                                                    \
    }

    int nw = T >> 3;
    int w2 = 0;
    if (fastld && nw >= 8) {
        const float4* s4 = (const float4*)row;
        float4 w0a = s4[0], w0b = s4[1];
        float4 w1a = s4[2], w1b = s4[3];
        float4 w2a = s4[4], w2b = s4[5];
        float4 w3a, w3b;
        for (; w2 + 4 <= nw; w2 += 4) {        // prefetch runs 3 windows ahead
            DOWIN(w0a, w0b, w3a, w3b, w2,     w2 + 3)
            DOWIN(w1a, w1b, w0a, w0b, w2 + 1, w2 + 4)
            DOWIN(w2a, w2b, w1a, w1b, w2 + 2, w2 + 5)
            DOWIN(w3a, w3b, w2a, w2b, w2 + 3, w2 + 6)
        }
    }
#undef DOWIN
#undef FIXUP
    for (int t = w2 * 8; t < T; ++t) {         // exact serial leftovers/tail
        float p = integ;
        float a = row[t];
        float x = p + a;
        if (x > THRESH) {
            if (n < MAXL) rec[n] = make_uint2(__float_as_uint(p), (unsigned)t);
            ++n;
            x = x - 1.0f;
        }
        integ = x;
    }
    nf[b] = (n < MAXL) ? (int)n : MAXL;
}

// Safety fallback for shapes that don't fit LDS (not used for T=2000):
// plain per-batch serial scan from global. Correct, slow.
__global__ __launch_bounds__(64) void cif_scan_fallback(
    const float* __restrict__ alphas, int T, int B,
    int* __restrict__ nf, uint2* __restrict__ recs) {
    int b = blockIdx.x * 64 + threadIdx.x;
    if (b >= B) return;
    const float* arow = alphas + (size_t)b * T;
    uint2* rec = recs + (size_t)b * RSTR;
    float integ = 0.0f;
    unsigned n = 0;
    for (int t = 0; t < T; ++t) {
        float p = integ;
        float x = p + arow[t];
        if (x > THRESH) {
            if (n < MAXL) rec[n] = make_uint2(__float_as_uint(p), (unsigned)t);
            ++n;
            x = x - 1.0f;
        }
        integ = x;
    }
    nf[b] = (n < MAXL) ? (int)n : MAXL;
}

// Kernel B (at HBM roofline, unchanged math; absmax 0.0 in rounds 1-7):
// one block per (batch,label), float4 over H, ascending-t accumulation.
//   out[b,k,:] = rem[k-1]*h[tp] + sum_{t in (tp,tf)} a_t*h[t] + dc_k*h[tf]
// dc = 1 - pre (bit-exact reference dist_completion), rem = a[tp] - dc_prev.
// Labels k >= fire count write zeros (d_out is poisoned by the harness).
__global__ __launch_bounds__(128) void cif_gather(
    const float* __restrict__ hidden, const float* __restrict__ alphas,
    int T, int H,
    const int* __restrict__ nf, const uint2* __restrict__ recs,
    float* __restrict__ out) {
    int b = blockIdx.x >> 6;
    int k = blockIdx.x & (MAXL - 1);

    int valid = (k < nf[b]);
    int tf = 0, t0 = 0, tp = 0;
    float rw = 0.0f, cw = 0.0f;
    const float* arow = alphas + (size_t)b * T;
    if (valid) {
        uint2 r = recs[(size_t)b * RSTR + k];
        cw = 1.0f - __uint_as_float(r.x);            // dc = 1 - pre, bit-exact
        tf = (int)r.y;
        if (k > 0) {
            uint2 rp = recs[(size_t)b * RSTR + k - 1];
            tp = (int)rp.y;
            float dcp = 1.0f - __uint_as_float(rp.x);
            rw = arow[tp] - dcp;                     // rem = a - dc, bit-exact
            t0 = tp + 1;
        }
    }

    if ((H & 3) == 0) {
        int W = H >> 2;
        const float4* hb4 = (const float4*)(hidden + (size_t)b * T * H);
        float4* out4 = (float4*)(out + (size_t)blockIdx.x * H);
        for (int h4 = threadIdx.x; h4 < W; h4 += blockDim.x) {
            float4 acc = make_float4(0.f, 0.f, 0.f, 0.f);
            if (valid) {
                if (k > 0) {
                    float4 m = hb4[(size_t)tp * W + h4];
                    acc.x = rw * m.x; acc.y = rw * m.y;
                    acc.z = rw * m.z; acc.w = rw * m.w;
                }
                for (int t = t0; t < tf; ++t) {
                    float4 m = hb4[(size_t)t * W + h4];
                    float a = arow[t];
                    acc.x += a * m.x; acc.y += a * m.y;
                    acc.z += a * m.z; acc.w += a * m.w;
                }
                float4 m = hb4[(size_t)tf * W + h4];
                acc.x += cw * m.x; acc.y += cw * m.y;
                acc.z += cw * m.z; acc.w += cw * m.w;
            }
            out4[h4] = acc;
        }
    } else {
        const float* hb = hidden + (size_t)b * T * H;
        size_t obase = (size_t)blockIdx.x * H;
        for (int h = threadIdx.x; h < H; h += blockDim.x) {
            float acc = 0.0f;
            if (valid) {
                if (k > 0) acc = rw * hb[(size_t)tp * H + h];
                for (int t = t0; t < tf; ++t)
                    acc += arow[t] * hb[(size_t)t * H + h];
                acc += cw * hb[(size_t)tf * H + h];
            }
            out[obase + h] = acc;
        }
    }
}

extern "C" void kernel_launch(void* const* d_in, const int* in_sizes, int n_in,
                              void* d_out, int out_size, void* d_ws, size_t ws_size,
                              hipStream_t stream) {
    const float* hidden = (const float*)d_in[0];
    const float* alphas = (const float*)d_in[1];
    float* out = (float*)d_out;

    long BT  = in_sizes[1];          // B*T
    long BTH = in_sizes[0];          // B*T*H
    int H = (int)(BTH / BT);         // 512
    int B = (int)((long)out_size / ((long)MAXL * H)); // 32
    int T = (int)(BT / B);           // 2000

    char* ws = (char*)d_ws;
    int*   nf   = (int*)ws;                          // B ints
    uint2* recs = (uint2*)(ws + 256);                // B*RSTR uint2

    if ((size_t)WPB * T + 16 <= (size_t)SAFL) {
        int nblk = (B + WPB - 1) / WPB;
        cif_scan<<<nblk, 1024, 0, stream>>>(alphas, T, B, nf, recs);
    } else {
        cif_scan_fallback<<<(B + 63) / 64, 64, 0, stream>>>(alphas, T, B, nf, recs);
    }
    cif_gather<<<B * MAXL, 128, 0, stream>>>(hidden, alphas, T, H, nf, recs, out);
}

// Round 9
// 60.215 us; speedup vs baseline: 1.9882x; 1.0870x over previous
//
#include <hip/hip_runtime.h>

#define THRESH 0.95f
#define MAXL 64
#define RSTR 65     // records per batch: 64 labels + 1 spare

// broadcast lane `lane`'s value of v to all lanes via v_readlane (SALU path,
// no LDS, no exec interaction; lane index is wave-uniform loop counter)
__device__ __forceinline__ float rlane(float v, int lane) {
    return __uint_as_float(__builtin_amdgcn_readlane(__float_as_uint(v), lane));
}

// Kernel A v9: register-resident speculative-window scan. ONE WAVE PER BATCH.
// Lane L holds window L of the current 64-window group (8 consecutive alphas,
// 2 float4s). The serial chain is computed redundantly by all 64 lanes:
// window w's 8 values are readlane-broadcast from lane w, then 8 chained adds
// (bit-exact prefix of the reference chain). alphas >= 0 (checked per group
// via sign-bit ballot) makes partials monotone -> single test s8 > 0.95.
// Fired windows take the exact serial replay (reference arithmetic verbatim:
// x = p + a; if (x > 0.95) { record pre; x -= 1.0 }). All branches are
// wave-uniform (no exec churn); record stores are all-lane same-address
// (HW-merged). NO memory access in the steady-state chain.
__global__ __launch_bounds__(64) void cif_scan(
    const float* __restrict__ alphas, int T, int B,
    int* __restrict__ nf, uint2* __restrict__ recs) {
    int b = blockIdx.x;
    if (b >= B) return;
    int lane = threadIdx.x;
    const float* arow = alphas + (size_t)b * T;
    uint2* rec = recs + (size_t)b * RSTR;

    float integ = 0.0f;
    unsigned n = 0;
    int nwin = T >> 3;
    bool fast = ((((uintptr_t)arow) & 15) == 0) && (nwin > 0);

    if (fast) {
        const float4* g4 = (const float4*)arow;
        int ngrp = (nwin + 63) >> 6;
        float4 z = make_float4(0.f, 0.f, 0.f, 0.f);
        float4 pa = z, pb = z, qa = z, qb = z;
        if (lane < nwin) { pa = g4[lane * 2]; pb = g4[lane * 2 + 1]; }
        for (int j = 0; j < ngrp; ++j) {
            int wbase = j << 6;
            int lim = nwin - wbase; if (lim > 64) lim = 64;
            if (j + 1 < ngrp) {               // prefetch next group (hidden
                int nx = wbase + 64 + lane;   // under this group's ~3k cyc)
                qa = z; qb = z;
                if (nx < nwin) { qa = g4[nx * 2]; qb = g4[nx * 2 + 1]; }
            }
            // group sign check: any negative alpha -> exact path every window
            unsigned sg = __float_as_uint(pa.x) | __float_as_uint(pa.y) |
                          __float_as_uint(pa.z) | __float_as_uint(pa.w) |
                          __float_as_uint(pb.x) | __float_as_uint(pb.y) |
                          __float_as_uint(pb.z) | __float_as_uint(pb.w);
            bool gneg = __ballot((sg >> 31) & 1u) != 0ull;

            for (int w2 = 0; w2 < lim; ++w2) {
                float c0 = rlane(pa.x, w2), c1 = rlane(pa.y, w2);
                float c2 = rlane(pa.z, w2), c3 = rlane(pa.w, w2);
                float c4 = rlane(pb.x, w2), c5 = rlane(pb.y, w2);
                float c6 = rlane(pb.z, w2), c7 = rlane(pb.w, w2);
                float s1 = integ + c0, s2 = s1 + c1;
                float s3 = s2 + c2,    s4 = s3 + c3;
                float s5 = s4 + c4,    s6 = s5 + c5;
                float s7 = s6 + c6,    s8 = s7 + c7;
                if (__builtin_expect((s8 > THRESH) || gneg, 0)) {
                    int tb = (wbase + w2) << 3;
                    float cur = integ;
                    float vv[8] = {c0, c1, c2, c3, c4, c5, c6, c7};
                    #pragma unroll
                    for (int ii = 0; ii < 8; ++ii) {
                        float p = cur;
                        float x = p + vv[ii];
                        if (x > THRESH) {     // wave-uniform (all lanes equal)
                            if (n < MAXL)
                                rec[n] = make_uint2(__float_as_uint(p),
                                                    (unsigned)(tb + ii));
                            ++n;
                            x = x - 1.0f;     // Sterbenz-exact
                        }
                        cur = x;
                    }
                    integ = cur;
                } else {
                    integ = s8;
                }
            }
            pa = qa; pb = qb;
        }
    }
    // tail steps (T % 8) — and the whole scan if the fast path doesn't apply.
    // All lanes load the same address (broadcast) and compute redundantly.
    int tstart = fast ? (nwin << 3) : 0;
    for (int t = tstart; t < T; ++t) {
        float p = integ;
        float x = p + arow[t];
        if (x > THRESH) {
            if (n < MAXL) rec[n] = make_uint2(__float_as_uint(p), (unsigned)t);
            ++n;
            x = x - 1.0f;
        }
        integ = x;
    }
    nf[b] = (n < MAXL) ? (int)n : MAXL;
}

// Kernel B (unchanged; absmax 0.0 in rounds 1-8; at L3-BW limit ~12 µs):
// one block per (batch,label), float4 over H, ascending-t accumulation.
//   out[b,k,:] = rem[k-1]*h[tp] + sum_{t in (tp,tf)} a_t*h[t] + dc_k*h[tf]
// dc = 1 - pre (bit-exact reference dist_completion), rem = a[tp] - dc_prev.
// Labels k >= fire count write zeros (d_out is poisoned by the harness).
__global__ __launch_bounds__(128) void cif_gather(
    const float* __restrict__ hidden, const float* __restrict__ alphas,
    int T, int H,
    const int* __restrict__ nf, const uint2* __restrict__ recs,
    float* __restrict__ out) {
    int b = blockIdx.x >> 6;
    int k = blockIdx.x & (MAXL - 1);

    int valid = (k < nf[b]);
    int tf = 0, t0 = 0, tp = 0;
    float rw = 0.0f, cw = 0.0f;
    const float* arow = alphas + (size_t)b * T;
    if (valid) {
        uint2 r = recs[(size_t)b * RSTR + k];
        cw = 1.0f - __uint_as_float(r.x);            // dc = 1 - pre, bit-exact
        tf = (int)r.y;
        if (k > 0) {
            uint2 rp = recs[(size_t)b * RSTR + k - 1];
            tp = (int)rp.y;
            float dcp = 1.0f - __uint_as_float(rp.x);
            rw = arow[tp] - dcp;                     // rem = a - dc, bit-exact
            t0 = tp + 1;
        }
    }

    if ((H & 3) == 0) {
        int W = H >> 2;
        const float4* hb4 = (const float4*)(hidden + (size_t)b * T * H);
        float4* out4 = (float4*)(out + (size_t)blockIdx.x * H);
        for (int h4 = threadIdx.x; h4 < W; h4 += blockDim.x) {
            float4 acc = make_float4(0.f, 0.f, 0.f, 0.f);
            if (valid) {
                if (k > 0) {
                    float4 m = hb4[(size_t)tp * W + h4];
                    acc.x = rw * m.x; acc.y = rw * m.y;
                    acc.z = rw * m.z; acc.w = rw * m.w;
                }
                for (int t = t0; t < tf; ++t) {
                    float4 m = hb4[(size_t)t * W + h4];
                    float a = arow[t];
                    acc.x += a * m.x; acc.y += a * m.y;
                    acc.z += a * m.z; acc.w += a * m.w;
                }
                float4 m = hb4[(size_t)tf * W + h4];
                acc.x += cw * m.x; acc.y += cw * m.y;
                acc.z += cw * m.z; acc.w += cw * m.w;
            }
            out4[h4] = acc;
        }
    } else {
        const float* hb = hidden + (size_t)b * T * H;
        size_t obase = (size_t)blockIdx.x * H;
        for (int h = threadIdx.x; h < H; h += blockDim.x) {
            float acc = 0.0f;
            if (valid) {
                if (k > 0) acc = rw * hb[(size_t)tp * H + h];
                for (int t = t0; t < tf; ++t)
                    acc += arow[t] * hb[(size_t)t * H + h];
                acc += cw * hb[(size_t)tf * H + h];
            }
            out[obase + h] = acc;
        }
    }
}

extern "C" void kernel_launch(void* const* d_in, const int* in_sizes, int n_in,
                              void* d_out, int out_size, void* d_ws, size_t ws_size,
                              hipStream_t stream) {
    const float* hidden = (const float*)d_in[0];
    const float* alphas = (const float*)d_in[1];
    float* out = (float*)d_out;

    long BT  = in_sizes[1];          // B*T
    long BTH = in_sizes[0];          // B*T*H
    int H = (int)(BTH / BT);         // 512
    int B = (int)((long)out_size / ((long)MAXL * H)); // 32
    int T = (int)(BT / B);           // 2000

    char* ws = (char*)d_ws;
    int*   nf   = (int*)ws;                          // B ints
    uint2* recs = (uint2*)(ws + 256);                // B*RSTR uint2

    cif_scan<<<B, 64, 0, stream>>>(alphas, T, B, nf, recs);
    cif_gather<<<B * MAXL, 128, 0, stream>>>(hidden, alphas, T, H, nf, recs, out);
}